// Round 10
// baseline (731.816 us; speedup 1.0000x reference)
//
#include <hip/hip_runtime.h>
#include <hip/hip_bf16.h>

typedef __attribute__((ext_vector_type(8))) short bf16x8;
typedef __attribute__((ext_vector_type(4))) float f32x4;

static constexpr int BB = 256;   // batch
static constexpr int TT = 33;    // time (input)
static constexpr int EE = 1024;  // embed
static constexpr int LL = 32;    // scan steps = T-1
static constexpr int NG = 4096;  // 4*E gate rows

static constexpr int BUF_SZ   = 20480;    // 16KB W + 4KB A
static constexpr int A_OFF    = 16384;
static constexpr int LDSG_OFF = 61440;    // 8KB gate exchange (3 bufs before it)
static constexpr int HH_OFF   = 69632;    // 1KB h tile
static constexpr int LDS_DYN  = 70656;

__device__ __forceinline__ short f2bf(float f) {
  unsigned u = __builtin_bit_cast(unsigned, f);
  u += 0x7fffu + ((u >> 16) & 1u);   // RNE
  return (short)(u >> 16);
}

__device__ __forceinline__ bf16x8 cvt8(f32x4 a, f32x4 b) {
  bf16x8 r;
  r[0] = f2bf(a[0]); r[1] = f2bf(a[1]); r[2] = f2bf(a[2]); r[3] = f2bf(a[3]);
  r[4] = f2bf(b[0]); r[5] = f2bf(b[1]); r[6] = f2bf(b[2]); r[7] = f2bf(b[3]);
  return r;
}

__device__ __forceinline__ float sigm(float x) { return 1.0f / (1.0f + __expf(-x)); }
__device__ __forceinline__ float tanh_f(float x) { return 1.0f - 2.0f / (__expf(2.0f * x) + 1.0f); }

// ---- prep: x fp32 -> bf16 [t][row][e]; c0 = x[:,1,:]; zero 512 flags
__global__ __launch_bounds__(256) void lstm_prep(
    const float* __restrict__ x, short* __restrict__ xbf, float* __restrict__ c_io,
    unsigned* __restrict__ flags)
{
  if (blockIdx.x == 0) {
    flags[(size_t)threadIdx.x * 64] = 0;
    flags[(size_t)(threadIdx.x + 256) * 64] = 0;
  }
  int gth = blockIdx.x * 256 + threadIdx.x;
  int eb  = gth & 127;
  int row = (gth >> 7) & 255;
  int t   = gth >> 15;
  const float* src = x + ((size_t)row * TT + t) * EE + (eb << 3);
  f32x4 lo = *(const f32x4*)src;
  f32x4 hi = *(const f32x4*)(src + 4);
  *(bf16x8*)(xbf + ((size_t)t * BB + row) * EE + (eb << 3)) = cvt8(lo, hi);
  if (t == 1) {
    float* cd = c_io + (size_t)row * EE + (eb << 3);
    *(f32x4*)cd = lo;
    *(f32x4*)(cd + 4) = hi;
  }
}

// ---- rec: 512 WGs x 256 thr — TWO independent pipelines per CU (coop-guaranteed
// co-residency). WG = 32 rows x 16 e-cols, 4 gate-waves (no duplicate W reads).
// 3 staging bufs (chunk = BK 64: W 16KB fp32 + A 4KB bf16), stage 3 ahead,
// vmcnt(10) counted waits (5 loads/chunk), 2 raw barriers/chunk.
// h: rotating per-t buffers, sc1 publish + per-WG flag (proven rounds 8/9).
__global__ __launch_bounds__(256) void lstm_rec(
    const short* __restrict__ xbf,   // [32][256][1024] bf16
    const float* __restrict__ Wih,   // [32][4096][1024]
    const float* __restrict__ Whh,   // [32][4096][1024]
    short* __restrict__ hroll,       // [32][256][1024] bf16 rotating
    float* __restrict__ c_io,        // [256][1024] fp32 (d_out c region)
    float* __restrict__ h_out,       // [256][1024] fp32 (d_out h region)
    unsigned* __restrict__ flags)    // [512] slots, 64-uint spacing
{
  extern __shared__ __align__(16) char smem[];

  const int tid  = threadIdx.x;
  const int lane = tid & 63;
  const int wv   = tid >> 6;      // 0..3 = gate
  const int g    = wv;
  const int lr   = lane & 15;
  const int kg   = lane >> 4;

  const int wg     = blockIdx.x;        // 0..511
  const int xcd    = wg & 7;
  const int jj     = wg >> 3;           // 0..63
  const int rowgrp = jj & 7;            // 8 x 32 rows
  const int ehi    = jj >> 3;           // 0..7
  const int e0     = (xcd * 8 + ehi) << 4;
  const int row0   = rowgrp << 5;

  const int rowW = g * 16 + lr;
  const int mw   = ((lr & 7) << 5) | ((lr & 8) << 1);
  const int ma   = (lr & 7) << 4;

  // hoisted staging constants (W: 4 x 16B/thread, A: 1 x 16B/thread)
  size_t wsrc_off[4]; int wdst_off[4];
#pragma unroll
  for (int r = 0; r < 4; ++r) {
    int o = r * 4096 + wv * 1024 + lane * 16;
    int lrow = o >> 8;
    int mwr = ((lrow & 7) << 5) | ((lrow & 8) << 1);
    wsrc_off[r] = (size_t)((lrow >> 4) * EE + e0 + (lrow & 15)) * 4096 + ((o & 255) ^ mwr);
    wdst_off[r] = r * 4096 + wv * 1024;
  }
  size_t asrc_off; int adst_off;
  {
    int o = wv * 1024 + lane * 16;
    int lrow = o >> 7;                  // 0..31
    asrc_off = (size_t)(row0 + lrow) * 2048 + ((o & 127) ^ ((lrow & 7) << 4));
    adst_off = A_OFF + wv * 1024;
  }

  const int rl   = tid >> 4;            // 0..15
  const int ecol = e0 + (tid & 15);
  float c0r = c_io[(size_t)(row0 + rl) * EE + ecol];
  float c1r = c_io[(size_t)(row0 + rl + 16) * EE + ecol];

  f32x4 acc0{}, acc1{};

  auto stageC = [&](int tt, int cc, int buf) {
    const int p  = cc >> 4;             // 0: x@Wih, 1: h@Whh
    const int k0 = (cc & 15) << 6;
    const char* Wt = (const char*)((p ? Whh : Wih) + (size_t)tt * NG * EE);
    const char* At = p ? (const char*)(hroll + (size_t)(tt - 1) * BB * EE)
                       : (const char*)(xbf + (size_t)tt * BB * EE);
    char* dst = smem + buf * BUF_SZ;
#pragma unroll
    for (int r = 0; r < 4; ++r)
      __builtin_amdgcn_global_load_lds(
          (const __attribute__((address_space(1))) unsigned int*)(Wt + wsrc_off[r] + (k0 << 2)),
          (__attribute__((address_space(3))) unsigned int*)(dst + wdst_off[r]), 16, 0, 0);
    __builtin_amdgcn_global_load_lds(
        (const __attribute__((address_space(1))) unsigned int*)(At + asrc_off + (k0 << 1)),
        (__attribute__((address_space(3))) unsigned int*)(dst + adst_off), 16, 0, 0);
  };

  auto compute = [&](int buf) {
    const char* Wb = smem + buf * BUF_SZ;
    const char* Ab = Wb + A_OFF;
#pragma unroll
    for (int kit = 0; kit < 2; ++kit) {
      int u5 = (kit * 4 + kg) << 5;
      f32x4 wlo = *(const f32x4*)(Wb + rowW * 256 + ((u5) ^ mw));
      f32x4 whi = *(const f32x4*)(Wb + rowW * 256 + ((u5 | 16) ^ mw));
      bf16x8 bfr = cvt8(wlo, whi);
      int u4 = ((kit * 4 + kg) << 4) ^ ma;
      bf16x8 a0 = *(const bf16x8*)(Ab + lr * 128 + u4);
      bf16x8 a1 = *(const bf16x8*)(Ab + (lr + 16) * 128 + u4);
      acc0 = __builtin_amdgcn_mfma_f32_16x16x32_bf16(a0, bfr, acc0, 0, 0, 0);
      acc1 = __builtin_amdgcn_mfma_f32_16x16x32_bf16(a1, bfr, acc1, 0, 0, 0);
    }
  };

  stageC(0, 0, 0);
  stageC(0, 1, 1);
  stageC(0, 2, 2);

  int fc3 = 0;    // flat chunk counter mod 3
  for (int t = 0; t < LL; ++t) {
    const int nch = t ? 32 : 16;
    for (int c = 0; c < nch; ++c) {
      if (t == LL - 1 && c == nch - 1)      asm volatile("s_waitcnt vmcnt(0)" ::: "memory");
      else if (t == LL - 1 && c == nch - 2) asm volatile("s_waitcnt vmcnt(5)" ::: "memory");
      else                                   asm volatile("s_waitcnt vmcnt(10)" ::: "memory");
      __builtin_amdgcn_s_barrier();
      compute(fc3);
      __builtin_amdgcn_s_barrier();

      int sc = c + 3, st = t;
      if (sc >= nch) { sc -= nch; st = t + 1; }
      bool skip = (st > t && sc == 2) || (st >= LL);   // (t+1,2) deferred; no step LL
      if (!skip) {
        if (st == t && sc == 16) {         // first phase-B stage needs h[t-1]
          if (tid < 64) {
            unsigned fid = (unsigned)((tid & 7) + 8 * rowgrp + 64 * (tid >> 3));
            while (__hip_atomic_load(flags + (size_t)fid * 64,
                                     __ATOMIC_RELAXED, __HIP_MEMORY_SCOPE_AGENT) < (unsigned)t)
              __builtin_amdgcn_s_sleep(1);
          }
          __builtin_amdgcn_s_barrier();
          __builtin_amdgcn_sched_barrier(0);
        }
        stageC(st, sc, fc3);               // same buf just computed (post-barrier safe)
      }
      fc3 = fc3 + 1; if (fc3 == 3) fc3 = 0;
    }

    // ---- epilogue (separate LDS area)
    float* ldsg = (float*)(smem + LDSG_OFF);
    short* hh   = (short*)(smem + HH_OFF);
#pragma unroll
    for (int j = 0; j < 4; ++j) {
      ldsg[(g * 32 + (kg << 2) + j) * 16 + lr]      = acc0[j];
      ldsg[(g * 32 + 16 + (kg << 2) + j) * 16 + lr] = acc1[j];
    }
    acc0 = f32x4{}; acc1 = f32x4{};
    asm volatile("s_waitcnt lgkmcnt(0)" ::: "memory");
    __builtin_amdgcn_s_barrier();

    {
      int el = tid & 15;
      float gi0 = ldsg[(0 * 32 + rl) * 16 + el];
      float gf0 = ldsg[(1 * 32 + rl) * 16 + el];
      float gg0 = ldsg[(2 * 32 + rl) * 16 + el];
      float go0 = ldsg[(3 * 32 + rl) * 16 + el];
      float gi1 = ldsg[(0 * 32 + rl + 16) * 16 + el];
      float gf1 = ldsg[(1 * 32 + rl + 16) * 16 + el];
      float gg1 = ldsg[(2 * 32 + rl + 16) * 16 + el];
      float go1 = ldsg[(3 * 32 + rl + 16) * 16 + el];

      c0r = sigm(gf0) * c0r + sigm(gi0) * tanh_f(gg0);
      float h0n = sigm(go0) * tanh_f(c0r);
      c1r = sigm(gf1) * c1r + sigm(gi1) * tanh_f(gg1);
      float h1n = sigm(go1) * tanh_f(c1r);

      hh[rl * 16 + el]        = f2bf(h0n);
      hh[(rl + 16) * 16 + el] = f2bf(h1n);

      if (t == LL - 1) {
        size_t o0 = (size_t)(row0 + rl) * EE + ecol;
        size_t o1 = (size_t)(row0 + rl + 16) * EE + ecol;
        h_out[o0] = h0n; c_io[o0] = c0r;
        h_out[o1] = h1n; c_io[o1] = c1r;
      }
    }
    asm volatile("s_waitcnt lgkmcnt(0)" ::: "memory");
    __builtin_amdgcn_s_barrier();

    if (t < LL - 1) {
      // publish h[t] (sc1 4B stores, 1 vm-op per wave), deferred stage, vmcnt proof
      {
        int r = tid >> 3, q = tid & 7;
        unsigned v = *(const unsigned*)((char*)hh + r * 32 + q * 4);
        __hip_atomic_store(
            (unsigned*)((char*)hroll + ((size_t)t * BB + row0 + r) * 2048 + (size_t)e0 * 2 + q * 4),
            v, __ATOMIC_RELAXED, __HIP_MEMORY_SCOPE_AGENT);
      }
      int bufd = fc3 == 0 ? 2 : fc3 - 1;   // buf of the deferred (t+1,2) slot
      stageC(t + 1, 2, bufd);
      asm volatile("s_waitcnt vmcnt(5)" ::: "memory");   // FIFO: publish store retired
      __builtin_amdgcn_s_barrier();                      // ...for all waves
      if (tid == 0)
        __hip_atomic_store(flags + (size_t)wg * 64, (unsigned)(t + 1),
                           __ATOMIC_RELAXED, __HIP_MEMORY_SCOPE_AGENT);
    }
  }
}

__global__ __launch_bounds__(256) void lstm_loss_part(
    const float* __restrict__ h, const float* __restrict__ tgt, float* __restrict__ partials)
{
  __shared__ float lds[4];
  int tid = threadIdx.x;
  float s = 0.f;
  int base = blockIdx.x * 1024 + tid;
#pragma unroll
  for (int q = 0; q < 4; ++q) {
    int idx = base + (q << 8);
    s += fabsf(h[idx] - tgt[idx]);
  }
#pragma unroll
  for (int off = 32; off > 0; off >>= 1) s += __shfl_down(s, off, 64);
  if ((tid & 63) == 0) lds[tid >> 6] = s;
  __syncthreads();
  if (tid == 0) partials[blockIdx.x] = lds[0] + lds[1] + lds[2] + lds[3];
}

__global__ __launch_bounds__(256) void lstm_loss_fin(
    const float* __restrict__ partials, float* __restrict__ out)
{
  __shared__ float lds[4];
  int tid = threadIdx.x;
  float s = partials[tid];
#pragma unroll
  for (int off = 32; off > 0; off >>= 1) s += __shfl_down(s, off, 64);
  if ((tid & 63) == 0) lds[tid >> 6] = s;
  __syncthreads();
  if (tid == 0) out[0] = (lds[0] + lds[1] + lds[2] + lds[3]) * (1.0f / 262144.0f);
}

extern "C" void kernel_launch(void* const* d_in, const int* in_sizes, int n_in,
                              void* d_out, int out_size, void* d_ws, size_t ws_size,
                              hipStream_t stream) {
  const float* x   = (const float*)d_in[0];
  const float* tgt = (const float*)d_in[1];
  const float* Wih = (const float*)d_in[2];
  const float* Whh = (const float*)d_in[3];

  float* out   = (float*)d_out;
  float* h_out = out + 1;                 // [256*1024]
  float* c_io  = out + 1 + BB * EE;       // [256*1024]

  // ws: xbf (16.8MB) | hroll 32 slots (16.8MB) | partials (1KB) | flags (128KB)
  short* xbf      = (short*)d_ws;
  short* hroll    = (short*)((char*)xbf + (size_t)LL * BB * EE * 2);
  float* partials = (float*)((char*)hroll + (size_t)LL * BB * EE * 2);
  unsigned* flags = (unsigned*)((char*)partials + 1024);

  static bool attr_done = false;
  if (!attr_done) {
    hipFuncSetAttribute((const void*)lstm_rec,
                        hipFuncAttributeMaxDynamicSharedMemorySize, LDS_DYN);
    attr_done = true;
  }

  lstm_prep<<<4096, 256, 0, stream>>>(x, xbf, c_io, flags);

  {
    const short* xbfA = xbf; const float* WihA = Wih; const float* WhhA = Whh;
    short* hrollA = hroll; float* cA = c_io; float* hA = h_out; unsigned* flagsA = flags;
    void* args[] = {&xbfA, &WihA, &WhhA, &hrollA, &cA, &hA, &flagsA};
    hipError_t e = hipLaunchCooperativeKernel((void*)lstm_rec, dim3(512), dim3(256),
                                              args, LDS_DYN, stream);
    if (e != hipSuccess)   // insurance vs silent coop rejection
      lstm_rec<<<512, 256, LDS_DYN, stream>>>(xbf, Wih, Whh, hroll, c_io, h_out, flags);
  }

  lstm_loss_part<<<256, 256, 0, stream>>>(h_out, tgt, partials);
  lstm_loss_fin<<<1, 256, 0, stream>>>(partials, out);
}

// Round 11
// 609.418 us; speedup vs baseline: 1.2008x; 1.2008x over previous
//
#include <hip/hip_runtime.h>
#include <hip/hip_bf16.h>

typedef __attribute__((ext_vector_type(8))) short bf16x8;
typedef __attribute__((ext_vector_type(4))) float f32x4;
typedef __attribute__((ext_vector_type(16))) float f32x16;

static constexpr int BB = 256;   // batch
static constexpr int TT = 33;    // time (input)
static constexpr int EE = 1024;  // embed
static constexpr int LL = 32;    // scan steps = T-1
static constexpr int NG = 4096;  // 4*E gate rows

static constexpr int BUF_SZ   = 24576;    // 16KB W fp32 + 8KB A bf16
static constexpr int A_OFF    = 16384;
static constexpr int RED_OFF  = 98304;    // 32KB k-reduction area (4 bufs before it)
static constexpr int LDSG_OFF = 131072;   // 16KB gate matrix [wcol][row]
static constexpr int HH_OFF   = 147456;   // 2KB h tile
static constexpr int LDS_DYN  = 149504;

__device__ __forceinline__ short f2bf(float f) {
  unsigned u = __builtin_bit_cast(unsigned, f);
  u += 0x7fffu + ((u >> 16) & 1u);   // RNE
  return (short)(u >> 16);
}

__device__ __forceinline__ bf16x8 cvt8(f32x4 a, f32x4 b) {
  bf16x8 r;
  r[0] = f2bf(a[0]); r[1] = f2bf(a[1]); r[2] = f2bf(a[2]); r[3] = f2bf(a[3]);
  r[4] = f2bf(b[0]); r[5] = f2bf(b[1]); r[6] = f2bf(b[2]); r[7] = f2bf(b[3]);
  return r;
}

__device__ __forceinline__ float sigm(float x) { return 1.0f / (1.0f + __expf(-x)); }
__device__ __forceinline__ float tanh_f(float x) { return 1.0f - 2.0f / (__expf(2.0f * x) + 1.0f); }

// ---- prep: x fp32 -> bf16 [t][row][e]; c0 = x[:,1,:]; zero 256 flags
__global__ __launch_bounds__(256) void lstm_prep(
    const float* __restrict__ x, short* __restrict__ xbf, float* __restrict__ c_io,
    unsigned* __restrict__ flags)
{
  if (blockIdx.x == 0) flags[(size_t)threadIdx.x * 64] = 0;
  int gth = blockIdx.x * 256 + threadIdx.x;
  int eb  = gth & 127;
  int row = (gth >> 7) & 255;
  int t   = gth >> 15;
  const float* src = x + ((size_t)row * TT + t) * EE + (eb << 3);
  f32x4 lo = *(const f32x4*)src;
  f32x4 hi = *(const f32x4*)(src + 4);
  *(bf16x8*)(xbf + ((size_t)t * BB + row) * EE + (eb << 3)) = cvt8(lo, hi);
  if (t == 1) {
    float* cd = c_io + (size_t)row * EE + (eb << 3);
    *(f32x4*)cd = lo;
    *(f32x4*)(cd + 4) = hi;
  }
}

// ---- rec: 256 WGs x 512 thr, 146KB dynamic LDS.
// Chunk pipeline skeleton = round 9 (4 bufs, stage 3 ahead, vmcnt(6), 1 barrier/chunk).
// NEW compute: 32x32x16 MFMA, wave (ct = wv&1 col-tile, kh = wv>>1 k-slice):
// B frag (W) read ONCE chip-wave-wide, A frags x2 -> LDS read 32KB/chunk (was 64KB).
// Per-step epilogue: LDS tree-reduce the 4 kh partials, then fused LSTM update.
__global__ __launch_bounds__(512) void lstm_rec(
    const short* __restrict__ xbf,   // [32][256][1024] bf16
    const float* __restrict__ Wih,   // [32][4096][1024]
    const float* __restrict__ Whh,   // [32][4096][1024]
    short* __restrict__ hroll,       // [32][256][1024] bf16 rotating
    float* __restrict__ c_io,        // [256][1024] fp32 (d_out c region)
    float* __restrict__ h_out,       // [256][1024] fp32 (d_out h region)
    unsigned* __restrict__ flags)    // [256] slots, 64-uint spacing
{
  extern __shared__ __align__(16) char smem[];

  const int tid  = threadIdx.x;
  const int lane = tid & 63;
  const int wv   = tid >> 6;      // 0..7
  const int ct   = wv & 1;        // col-tile (32 W-rows = 2 gates)
  const int kh   = wv >> 1;       // k-slice 0..3 within BK=64

  const int wg     = blockIdx.x;        // 0..255
  const int xcd    = wg & 7;
  const int jj     = wg >> 3;
  const int rowgrp = jj & 3;            // 4 x 64 rows
  const int ehi    = jj >> 2;           // 0..7
  const int e0     = (xcd * 8 + ehi) << 4;
  const int row0   = rowgrp << 6;

  // ---- staging constants (identical scheme to rounds 8/9; 3 loads/thread/chunk)
  size_t wsrc_off[2]; int wdst_off[2];
#pragma unroll
  for (int r = 0; r < 2; ++r) {
    int o = r * 8192 + wv * 1024 + lane * 16;
    int lrow = o >> 8;
    int mwr = ((lrow & 7) << 5) | ((lrow & 8) << 1);
    wsrc_off[r] = (size_t)((lrow >> 4) * EE + e0 + (lrow & 15)) * 4096 + ((o & 255) ^ mwr);
    wdst_off[r] = r * 8192 + wv * 1024;
  }
  size_t asrc_off; int adst_off;
  {
    int o = wv * 1024 + lane * 16;
    int lrow = o >> 7;                  // 0..63
    asrc_off = (size_t)(row0 + lrow) * 2048 + ((o & 127) ^ ((lrow & 7) << 4));
    adst_off = A_OFF + wv * 1024;
  }

  // ---- compute constants (hoisted, lane-invariant per thread)
  const int wrow    = ct * 32 + (lane & 31);
  const int mwr2    = ((wrow & 7) << 5) | ((wrow & 8) << 1);
  const int kW      = kh * 64 + ((lane >> 5) << 5);
  const int woff_lo = wrow * 256 + (kW ^ mwr2);
  const int woff_hi = wrow * 256 + ((kW + 16) ^ mwr2);
  const int arow    = lane & 31;
  const int kA      = kh * 32 + ((lane >> 5) << 4);
  const int aoff0   = arow * 128 + (kA ^ ((arow & 7) << 4));
  const int aoff1   = aoff0 + 4096;     // rows +32 (same swizzle: (arow+32)&7 == arow&7)

  // ---- epilogue element ownership: (row er, ecols ee_ and ee_+8)
  const int er  = tid & 63;
  const int ee_ = tid >> 6;             // 0..7
  float c0r = c_io[(size_t)(row0 + er) * EE + e0 + ee_];
  float c1r = c_io[(size_t)(row0 + er) * EE + e0 + ee_ + 8];

  f32x16 acc0{}, acc1{};   // k-partial tiles (rt=0: rows 0-31, rt=1: rows 32-63)

  auto stageC = [&](int tt, int cc, int buf) {
    const int p  = cc >> 4;             // 0: x@Wih, 1: h@Whh
    const int k0 = (cc & 15) << 6;
    const char* Wt = (const char*)((p ? Whh : Wih) + (size_t)tt * NG * EE);
    const char* At = p ? (const char*)(hroll + (size_t)(tt - 1) * BB * EE)
                       : (const char*)(xbf + (size_t)tt * BB * EE);
    char* dst = smem + buf * BUF_SZ;
#pragma unroll
    for (int r = 0; r < 2; ++r)
      __builtin_amdgcn_global_load_lds(
          (const __attribute__((address_space(1))) unsigned int*)(Wt + wsrc_off[r] + (k0 << 2)),
          (__attribute__((address_space(3))) unsigned int*)(dst + wdst_off[r]), 16, 0, 0);
    __builtin_amdgcn_global_load_lds(
        (const __attribute__((address_space(1))) unsigned int*)(At + asrc_off + (k0 << 1)),
        (__attribute__((address_space(3))) unsigned int*)(dst + adst_off), 16, 0, 0);
  };

  auto compute = [&](int buf) {
    const char* Wb = smem + buf * BUF_SZ;
    const char* Ab = Wb + A_OFF;
    f32x4 wlo = *(const f32x4*)(Wb + woff_lo);
    f32x4 whi = *(const f32x4*)(Wb + woff_hi);
    bf16x8 bfr = cvt8(wlo, whi);
    bf16x8 a0 = *(const bf16x8*)(Ab + aoff0);
    bf16x8 a1 = *(const bf16x8*)(Ab + aoff1);
    acc0 = __builtin_amdgcn_mfma_f32_32x32x16_bf16(a0, bfr, acc0, 0, 0, 0);
    acc1 = __builtin_amdgcn_mfma_f32_32x32x16_bf16(a1, bfr, acc1, 0, 0, 0);
  };

  // reduction slot helpers: slot(ct, src, rt) = 4KB tile dumps, swizzled 16B granules
  float* red = (float*)(smem + RED_OFF);
  const int rsw = (lane & 3) << 4;
  auto slotp = [&](int src, int rt) { return red + (size_t)(((ct * 2 + src) * 2 + rt)) * 1024; };
  auto dumpT = [&](float* base, const f32x16& a) {
    char* b = (char*)base + lane * 64;
#pragma unroll
    for (int jq = 0; jq < 4; ++jq) {
      f32x4 v{a[jq * 4 + 0], a[jq * 4 + 1], a[jq * 4 + 2], a[jq * 4 + 3]};
      *(f32x4*)(b + ((jq * 16) ^ rsw)) = v;
    }
  };
  auto addT = [&](const float* base, f32x16& a) {
    const char* b = (const char*)base + lane * 64;
#pragma unroll
    for (int jq = 0; jq < 4; ++jq) {
      f32x4 v = *(const f32x4*)(b + ((jq * 16) ^ rsw));
      a[jq * 4 + 0] += v[0]; a[jq * 4 + 1] += v[1];
      a[jq * 4 + 2] += v[2]; a[jq * 4 + 3] += v[3];
    }
  };

  stageC(0, 0, 0);
  stageC(0, 1, 1);
  stageC(0, 2, 2);

  int fc = 0;   // flat chunk counter
  for (int t = 0; t < LL; ++t) {
    const int nch = t ? 32 : 16;
    for (int c = 0; c < nch; ++c, ++fc) {
      if (t == LL - 1 && c == nch - 1)      asm volatile("s_waitcnt vmcnt(0)" ::: "memory");
      else if (t == LL - 1 && c == nch - 2) asm volatile("s_waitcnt vmcnt(3)" ::: "memory");
      else                                   asm volatile("s_waitcnt vmcnt(6)" ::: "memory");
      __builtin_amdgcn_s_barrier();
      compute(fc & 3);

      int sc = c + 3, st = t;
      if (sc >= nch) { sc -= nch; st = t + 1; }
      bool skip = (st > t && sc == 2) || (st >= LL);   // (t+1,2) deferred; no step LL
      if (!skip) {
        if (st == t && sc == 16) {         // first phase-B stage needs h[t-1]
          if (tid < 256) {
            while (__hip_atomic_load(flags + (size_t)tid * 64,
                                     __ATOMIC_RELAXED, __HIP_MEMORY_SCOPE_AGENT) < (unsigned)t)
              __builtin_amdgcn_s_sleep(1);
          }
          __builtin_amdgcn_s_barrier();
          __builtin_amdgcn_sched_barrier(0);
        }
        stageC(st, sc, (fc + 3) & 3);
      }
    }

    // ---- epilogue: reduce 4 kh partials, fused LSTM update
    if (kh >= 2) { dumpT(slotp(kh - 2, 0), acc0); dumpT(slotp(kh - 2, 1), acc1); }
    asm volatile("s_waitcnt lgkmcnt(0)" ::: "memory");
    __builtin_amdgcn_s_barrier();
    if (kh < 2) { addT(slotp(kh, 0), acc0); addT(slotp(kh, 1), acc1); }
    asm volatile("s_waitcnt lgkmcnt(0)" ::: "memory");
    __builtin_amdgcn_s_barrier();
    if (kh == 1) { dumpT(slotp(0, 0), acc0); dumpT(slotp(0, 1), acc1); }
    asm volatile("s_waitcnt lgkmcnt(0)" ::: "memory");
    __builtin_amdgcn_s_barrier();
    if (kh == 0) {
      addT(slotp(0, 0), acc0);
      addT(slotp(0, 1), acc1);
      // write full gate matrix to ldsg[wcol][row] (swizzled), wcol = ct*32+(lane&31)
      const int swc = mwr2;               // same mask family, wrow == wcol here
      char* gb = (char*)(smem + LDSG_OFF) + wrow * 256;
#pragma unroll
      for (int rt = 0; rt < 2; ++rt) {
        const f32x16& a = rt ? acc1 : acc0;
#pragma unroll
        for (int jq = 0; jq < 4; ++jq) {
          int rowb = rt * 128 + jq * 32 + ((lane >> 5) << 4);
          f32x4 v{a[jq * 4 + 0], a[jq * 4 + 1], a[jq * 4 + 2], a[jq * 4 + 3]};
          *(f32x4*)(gb + (rowb ^ swc)) = v;
        }
      }
    }
    acc0 = f32x16{}; acc1 = f32x16{};
    asm volatile("s_waitcnt lgkmcnt(0)" ::: "memory");
    __builtin_amdgcn_s_barrier();

    {
      const char* gbase = (const char*)(smem + LDSG_OFF);
      short* hh = (short*)(smem + HH_OFF);
      auto gate = [&](int g, int ee) {
        int wc = g * 16 + ee;
        int swc = ((wc & 7) << 5) | ((wc & 8) << 1);
        return *(const float*)(gbase + wc * 256 + ((er * 4) ^ swc));
      };
      float gi0 = gate(0, ee_), gf0 = gate(1, ee_), gg0 = gate(2, ee_), go0 = gate(3, ee_);
      float gi1 = gate(0, ee_ + 8), gf1 = gate(1, ee_ + 8), gg1 = gate(2, ee_ + 8), go1 = gate(3, ee_ + 8);

      c0r = sigm(gf0) * c0r + sigm(gi0) * tanh_f(gg0);
      float h0n = sigm(go0) * tanh_f(c0r);
      c1r = sigm(gf1) * c1r + sigm(gi1) * tanh_f(gg1);
      float h1n = sigm(go1) * tanh_f(c1r);

      hh[er * 16 + ee_]     = f2bf(h0n);
      hh[er * 16 + ee_ + 8] = f2bf(h1n);

      if (t == LL - 1) {
        size_t o0 = (size_t)(row0 + er) * EE + e0 + ee_;
        size_t o1 = o0 + 8;
        h_out[o0] = h0n; c_io[o0] = c0r;
        h_out[o1] = h1n; c_io[o1] = c1r;
      }
    }
    asm volatile("s_waitcnt lgkmcnt(0)" ::: "memory");
    __builtin_amdgcn_s_barrier();

    if (t < LL - 1) {
      // publish h[t] (sc1 -> L3), deferred (t+1,2) stage, vmcnt proof, flag
      if (tid < 256) {
        int r = tid >> 2, q = tid & 3;
        unsigned long long v = *(const unsigned long long*)(smem + HH_OFF + r * 32 + q * 8);
        __hip_atomic_store(
            (unsigned long long*)((char*)hroll + ((size_t)t * BB + row0 + r) * 2048 + (size_t)e0 * 2 + q * 8),
            v, __ATOMIC_RELAXED, __HIP_MEMORY_SCOPE_AGENT);
      }
      stageC(t + 1, 2, (fc + 2) & 3);
      asm volatile("s_waitcnt vmcnt(3)" ::: "memory");   // in-order: publish retired
      __builtin_amdgcn_s_barrier();                      // ...for all waves
      if (tid == 0)
        __hip_atomic_store(flags + (size_t)wg * 64, (unsigned)(t + 1),
                           __ATOMIC_RELAXED, __HIP_MEMORY_SCOPE_AGENT);
    }
  }
}

__global__ __launch_bounds__(256) void lstm_loss_part(
    const float* __restrict__ h, const float* __restrict__ tgt, float* __restrict__ partials)
{
  __shared__ float lds[4];
  int tid = threadIdx.x;
  float s = 0.f;
  int base = blockIdx.x * 1024 + tid;
#pragma unroll
  for (int q = 0; q < 4; ++q) {
    int idx = base + (q << 8);
    s += fabsf(h[idx] - tgt[idx]);
  }
#pragma unroll
  for (int off = 32; off > 0; off >>= 1) s += __shfl_down(s, off, 64);
  if ((tid & 63) == 0) lds[tid >> 6] = s;
  __syncthreads();
  if (tid == 0) partials[blockIdx.x] = lds[0] + lds[1] + lds[2] + lds[3];
}

__global__ __launch_bounds__(256) void lstm_loss_fin(
    const float* __restrict__ partials, float* __restrict__ out)
{
  __shared__ float lds[4];
  int tid = threadIdx.x;
  float s = partials[tid];
#pragma unroll
  for (int off = 32; off > 0; off >>= 1) s += __shfl_down(s, off, 64);
  if ((tid & 63) == 0) lds[tid >> 6] = s;
  __syncthreads();
  if (tid == 0) out[0] = (lds[0] + lds[1] + lds[2] + lds[3]) * (1.0f / 262144.0f);
}

extern "C" void kernel_launch(void* const* d_in, const int* in_sizes, int n_in,
                              void* d_out, int out_size, void* d_ws, size_t ws_size,
                              hipStream_t stream) {
  const float* x   = (const float*)d_in[0];
  const float* tgt = (const float*)d_in[1];
  const float* Wih = (const float*)d_in[2];
  const float* Whh = (const float*)d_in[3];

  float* out   = (float*)d_out;
  float* h_out = out + 1;                 // [256*1024]
  float* c_io  = out + 1 + BB * EE;       // [256*1024]

  // ws: xbf (16.8MB) | hroll 32 slots (16.8MB) | partials (1KB) | flags (64KB)
  short* xbf      = (short*)d_ws;
  short* hroll    = (short*)((char*)xbf + (size_t)LL * BB * EE * 2);
  float* partials = (float*)((char*)hroll + (size_t)LL * BB * EE * 2);
  unsigned* flags = (unsigned*)((char*)partials + 1024);

  static bool attr_done = false;
  if (!attr_done) {
    hipFuncSetAttribute((const void*)lstm_rec,
                        hipFuncAttributeMaxDynamicSharedMemorySize, LDS_DYN);
    attr_done = true;
  }

  lstm_prep<<<4096, 256, 0, stream>>>(x, xbf, c_io, flags);

  {
    const short* xbfA = xbf; const float* WihA = Wih; const float* WhhA = Whh;
    short* hrollA = hroll; float* cA = c_io; float* hA = h_out; unsigned* flagsA = flags;
    void* args[] = {&xbfA, &WihA, &WhhA, &hrollA, &cA, &hA, &flagsA};
    hipError_t e = hipLaunchCooperativeKernel((void*)lstm_rec, dim3(256), dim3(512),
                                              args, LDS_DYN, stream);
    if (e != hipSuccess)   // insurance vs silent coop rejection
      lstm_rec<<<256, 512, LDS_DYN, stream>>>(xbf, Wih, Whh, hroll, c_io, h_out, flags);
  }

  lstm_loss_part<<<256, 256, 0, stream>>>(h_out, tgt, partials);
  lstm_loss_fin<<<1, 256, 0, stream>>>(partials, out);
}

// Round 12
// 541.041 us; speedup vs baseline: 1.3526x; 1.1264x over previous
//
#include <hip/hip_runtime.h>
#include <hip/hip_bf16.h>

typedef __attribute__((ext_vector_type(8))) short bf16x8;
typedef __attribute__((ext_vector_type(4))) float f32x4;
typedef __attribute__((ext_vector_type(16))) float f32x16;

static constexpr int BB = 256;   // batch
static constexpr int TT = 33;    // time (input)
static constexpr int EE = 1024;  // embed
static constexpr int LL = 32;    // scan steps = T-1
static constexpr int NG = 4096;  // 4*E gate rows

static constexpr int BUF_SZ  = 24576;    // 16KB W fp32 + 8KB A bf16
static constexpr int A_OFF   = 16384;
static constexpr int NBUF    = 6;
static constexpr int LDS_DYN = 147456;   // 6 bufs; epilogue aliases 2 idle bufs

__device__ __forceinline__ short f2bf(float f) {
  unsigned u = __builtin_bit_cast(unsigned, f);
  u += 0x7fffu + ((u >> 16) & 1u);   // RNE
  return (short)(u >> 16);
}

__device__ __forceinline__ bf16x8 cvt8(f32x4 a, f32x4 b) {
  bf16x8 r;
  r[0] = f2bf(a[0]); r[1] = f2bf(a[1]); r[2] = f2bf(a[2]); r[3] = f2bf(a[3]);
  r[4] = f2bf(b[0]); r[5] = f2bf(b[1]); r[6] = f2bf(b[2]); r[7] = f2bf(b[3]);
  return r;
}

__device__ __forceinline__ float sigm(float x) { return 1.0f / (1.0f + __expf(-x)); }
__device__ __forceinline__ float tanh_f(float x) { return 1.0f - 2.0f / (__expf(2.0f * x) + 1.0f); }

// ---- prep: x fp32 -> bf16 [t][row][e]; c0 = x[:,1,:]; zero 256 flags
__global__ __launch_bounds__(256) void lstm_prep(
    const float* __restrict__ x, short* __restrict__ xbf, float* __restrict__ c_io,
    unsigned* __restrict__ flags)
{
  if (blockIdx.x == 0) flags[(size_t)threadIdx.x * 64] = 0;
  int gth = blockIdx.x * 256 + threadIdx.x;
  int eb  = gth & 127;
  int row = (gth >> 7) & 255;
  int t   = gth >> 15;
  const float* src = x + ((size_t)row * TT + t) * EE + (eb << 3);
  f32x4 lo = *(const f32x4*)src;
  f32x4 hi = *(const f32x4*)(src + 4);
  *(bf16x8*)(xbf + ((size_t)t * BB + row) * EE + (eb << 3)) = cvt8(lo, hi);
  if (t == 1) {
    float* cd = c_io + (size_t)row * EE + (eb << 3);
    *(f32x4*)cd = lo;
    *(f32x4*)(cd + 4) = hi;
  }
}

// ---- rec: 256 WGs x 512 thr, 144KB dynamic LDS (6 bufs).
// PAIR pipeline: 2 chunks per {vmcnt(6) -> barrier -> compute x2 -> stage pair}.
// A stored row-pair interleaved (256B pairs, s = (2g+(r&1)) ^ ((rp&7)<<1)):
// k-slice reads spread 16 granule slots -> 2-way (free). W layout unchanged.
// Epilogue: kh-partial tree-reduction in the 2 just-freed bufs (flat mod-6 safe),
// reduction swizzle ((lane>>1)&3)<<4 = 8-way min. Publish/flag protocol proven r8-r11.
__global__ __launch_bounds__(512) void lstm_rec(
    const short* __restrict__ xbf,   // [32][256][1024] bf16
    const float* __restrict__ Wih,   // [32][4096][1024]
    const float* __restrict__ Whh,   // [32][4096][1024]
    short* __restrict__ hroll,       // [32][256][1024] bf16 rotating
    float* __restrict__ c_io,        // [256][1024] fp32 (d_out c region)
    float* __restrict__ h_out,       // [256][1024] fp32 (d_out h region)
    unsigned* __restrict__ flags)    // [256] slots, 64-uint spacing
{
  extern __shared__ __align__(16) char smem[];

  const int tid  = threadIdx.x;
  const int lane = tid & 63;
  const int wv   = tid >> 6;      // 0..7
  const int ct   = wv & 1;        // col-tile (32 W-rows = 2 gates)
  const int kh   = wv >> 1;       // k-slice 0..3 within BK=64

  const int wg     = blockIdx.x;        // 0..255
  const int xcd    = wg & 7;
  const int jj     = wg >> 3;
  const int rowgrp = jj & 3;            // 4 x 64 rows
  const int ehi    = jj >> 2;           // 0..7
  const int e0     = (xcd * 8 + ehi) << 4;
  const int row0   = rowgrp << 6;

  // ---- staging constants: W identical to r9/r11; A = row-pair interleave inverse
  size_t wsrc_off[2]; int wdst_off[2];
#pragma unroll
  for (int r = 0; r < 2; ++r) {
    int o = r * 8192 + wv * 1024 + lane * 16;
    int lrow = o >> 8;
    int mwr = ((lrow & 7) << 5) | ((lrow & 8) << 1);
    wsrc_off[r] = (size_t)((lrow >> 4) * EE + e0 + (lrow & 15)) * 4096 + ((o & 255) ^ mwr);
    wdst_off[r] = r * 8192 + wv * 1024;
  }
  size_t asrc_off; int adst_off;
  {
    int o  = wv * 1024 + lane * 16;     // dest byte in A region (linear)
    int G  = o >> 4;                    // granule 0..511
    int rp = G >> 4;                    // row-pair 0..31
    int s  = G & 15;
    int r  = rp * 2 + (s & 1);
    int g  = ((s >> 1) ^ (rp & 7)) & 7;
    asrc_off = (size_t)(row0 + r) * 2048 + g * 16;
    adst_off = A_OFF + o;
  }

  // ---- compute constants
  const int wrow    = ct * 32 + (lane & 31);
  const int mwr2    = ((wrow & 7) << 5) | ((wrow & 8) << 1);
  const int kW      = kh * 64 + ((lane >> 5) << 5);
  const int woff_lo = wrow * 256 + (kW ^ mwr2);
  const int woff_hi = wrow * 256 + ((kW + 16) ^ mwr2);
  const int arow    = lane & 31;
  const int rpA     = arow >> 1;
  const int gkh     = kh * 2 + (lane >> 5);
  const int sA      = (2 * gkh + (arow & 1)) ^ ((rpA & 7) << 1);
  const int aoff0   = rpA * 256 + sA * 16;     // +4096 for rows 32..63

  // ---- epilogue element ownership
  const int er  = tid & 63;
  const int ee_ = tid >> 6;             // 0..7
  float c0r = c_io[(size_t)(row0 + er) * EE + e0 + ee_];
  float c1r = c_io[(size_t)(row0 + er) * EE + e0 + ee_ + 8];

  f32x16 acc0{}, acc1{};   // k-partials (rows 0-31, 32-63)

  auto stageC = [&](int tt, int cc, int buf) {
    const int p  = cc >> 4;             // 0: x@Wih, 1: h@Whh
    const int k0 = (cc & 15) << 6;
    const char* Wt = (const char*)((p ? Whh : Wih) + (size_t)tt * NG * EE);
    const char* At = p ? (const char*)(hroll + (size_t)(tt - 1) * BB * EE)
                       : (const char*)(xbf + (size_t)tt * BB * EE);
    char* dst = smem + buf * BUF_SZ;
#pragma unroll
    for (int r = 0; r < 2; ++r)
      __builtin_amdgcn_global_load_lds(
          (const __attribute__((address_space(1))) unsigned int*)(Wt + wsrc_off[r] + (k0 << 2)),
          (__attribute__((address_space(3))) unsigned int*)(dst + wdst_off[r]), 16, 0, 0);
    __builtin_amdgcn_global_load_lds(
        (const __attribute__((address_space(1))) unsigned int*)(At + asrc_off + (k0 << 1)),
        (__attribute__((address_space(3))) unsigned int*)(dst + adst_off), 16, 0, 0);
  };

  auto compute = [&](int buf) {
    const char* Wb = smem + buf * BUF_SZ;
    const char* Ab = Wb + A_OFF;
    f32x4 wlo = *(const f32x4*)(Wb + woff_lo);
    f32x4 whi = *(const f32x4*)(Wb + woff_hi);
    bf16x8 bfr = cvt8(wlo, whi);
    bf16x8 a0 = *(const bf16x8*)(Ab + aoff0);
    bf16x8 a1 = *(const bf16x8*)(Ab + aoff0 + 4096);
    acc0 = __builtin_amdgcn_mfma_f32_32x32x16_bf16(a0, bfr, acc0, 0, 0, 0);
    acc1 = __builtin_amdgcn_mfma_f32_32x32x16_bf16(a1, bfr, acc1, 0, 0, 0);
  };

  const int rsw = ((lane >> 1) & 3) << 4;   // 8-way min (was 16-way)
  auto dumpT = [&](float* base, const f32x16& a) {
    char* b = (char*)base + lane * 64;
#pragma unroll
    for (int jq = 0; jq < 4; ++jq) {
      f32x4 v{a[jq * 4 + 0], a[jq * 4 + 1], a[jq * 4 + 2], a[jq * 4 + 3]};
      *(f32x4*)(b + ((jq * 16) ^ rsw)) = v;
    }
  };
  auto addT = [&](const float* base, f32x16& a) {
    const char* b = (const char*)base + lane * 64;
#pragma unroll
    for (int jq = 0; jq < 4; ++jq) {
      f32x4 v = *(const f32x4*)(b + ((jq * 16) ^ rsw));
      a[jq * 4 + 0] += v[0]; a[jq * 4 + 1] += v[1];
      a[jq * 4 + 2] += v[2]; a[jq * 4 + 3] += v[3];
    }
  };

  // prologue: stage pairs 0,1 (chunks 0-3)
  stageC(0, 0, 0); stageC(0, 1, 1); stageC(0, 2, 2); stageC(0, 3, 3);

  int fb = 0;   // buf index of current pair's first chunk (flat chunk % 6)
  for (int t = 0; t < LL; ++t) {
    const int nch = t ? 32 : 16;
    for (int pc = 0; pc < nch / 2; ++pc) {
      if (t == LL - 1 && pc == nch / 2 - 1) asm volatile("s_waitcnt vmcnt(0)" ::: "memory");
      else                                   asm volatile("s_waitcnt vmcnt(6)" ::: "memory");
      __builtin_amdgcn_s_barrier();
      compute(fb);
      compute((fb + 1) % NBUF);

      int sc0 = 2 * pc + 4, st = t;
      if (sc0 >= nch) { sc0 -= nch; st = t + 1; }
      bool skip = (st > t && sc0 == 2) || (st >= LL);   // pair {2,3} deferred
      if (!skip) {
        if (st == t && sc0 == 16) {        // first phase-B pair needs h[t-1]
          if (tid < 256) {
            while (__hip_atomic_load(flags + (size_t)tid * 64,
                                     __ATOMIC_RELAXED, __HIP_MEMORY_SCOPE_AGENT) < (unsigned)t)
              __builtin_amdgcn_s_sleep(1);
          }
          __builtin_amdgcn_s_barrier();
          __builtin_amdgcn_sched_barrier(0);
        }
        stageC(st, sc0,     (fb + 4) % NBUF);
        stageC(st, sc0 + 1, (fb + 5) % NBUF);
      }
      fb = (fb + 2) % NBUF;
    }

    // ---- epilogue: red = last pair's c0 buf, ldsg/hh = last pair's c1 buf
    float* red  = (float*)(smem + (size_t)((fb + 4) % NBUF) * BUF_SZ);
    char*  glsb = smem + (size_t)((fb + 5) % NBUF) * BUF_SZ;
    auto slotp = [&](int src, int rt) { return red + (size_t)((ct * 2 + src) * 2 + rt) * 1024; };

    if (kh >= 2) { dumpT(slotp(kh - 2, 0), acc0); dumpT(slotp(kh - 2, 1), acc1); }
    asm volatile("s_waitcnt lgkmcnt(0)" ::: "memory");
    __builtin_amdgcn_s_barrier();
    if (kh < 2) { addT(slotp(kh, 0), acc0); addT(slotp(kh, 1), acc1); }
    asm volatile("s_waitcnt lgkmcnt(0)" ::: "memory");
    __builtin_amdgcn_s_barrier();
    if (kh == 1) { dumpT(slotp(0, 0), acc0); dumpT(slotp(0, 1), acc1); }
    asm volatile("s_waitcnt lgkmcnt(0)" ::: "memory");
    __builtin_amdgcn_s_barrier();
    if (kh == 0) {
      addT(slotp(0, 0), acc0);
      addT(slotp(0, 1), acc1);
      char* gb = glsb + wrow * 256;       // gate matrix [wcol][row], swizzled
#pragma unroll
      for (int rt = 0; rt < 2; ++rt) {
        const f32x16& a = rt ? acc1 : acc0;
#pragma unroll
        for (int jq = 0; jq < 4; ++jq) {
          int rowb = rt * 128 + jq * 32 + ((lane >> 5) << 4);
          f32x4 v{a[jq * 4 + 0], a[jq * 4 + 1], a[jq * 4 + 2], a[jq * 4 + 3]};
          *(f32x4*)(gb + (rowb ^ mwr2)) = v;
        }
      }
    }
    acc0 = f32x16{}; acc1 = f32x16{};
    asm volatile("s_waitcnt lgkmcnt(0)" ::: "memory");
    __builtin_amdgcn_s_barrier();

    {
      short* hh = (short*)(glsb + 16384);
      auto gate = [&](int g, int ee) {
        int wc = g * 16 + ee;
        int swc = ((wc & 7) << 5) | ((wc & 8) << 1);
        return *(const float*)(glsb + wc * 256 + ((er * 4) ^ swc));
      };
      float gi0 = gate(0, ee_), gf0 = gate(1, ee_), gg0 = gate(2, ee_), go0 = gate(3, ee_);
      float gi1 = gate(0, ee_ + 8), gf1 = gate(1, ee_ + 8), gg1 = gate(2, ee_ + 8), go1 = gate(3, ee_ + 8);

      c0r = sigm(gf0) * c0r + sigm(gi0) * tanh_f(gg0);
      float h0n = sigm(go0) * tanh_f(c0r);
      c1r = sigm(gf1) * c1r + sigm(gi1) * tanh_f(gg1);
      float h1n = sigm(go1) * tanh_f(c1r);

      hh[er * 16 + ee_]     = f2bf(h0n);
      hh[er * 16 + ee_ + 8] = f2bf(h1n);

      if (t == LL - 1) {
        size_t o0 = (size_t)(row0 + er) * EE + e0 + ee_;
        size_t o1 = o0 + 8;
        h_out[o0] = h0n; c_io[o0] = c0r;
        h_out[o1] = h1n; c_io[o1] = c1r;
      }
    }
    asm volatile("s_waitcnt lgkmcnt(0)" ::: "memory");
    __builtin_amdgcn_s_barrier();

    if (t < LL - 1) {
      // publish h[t] (sc1 -> L3), deferred pair (t+1,{2,3}), vmcnt(6) proof, flag
      if (tid < 256) {
        int r = tid >> 2, q = tid & 3;
        unsigned long long v = *(const unsigned long long*)(glsb + 16384 + r * 32 + q * 8);
        __hip_atomic_store(
            (unsigned long long*)((char*)hroll + ((size_t)t * BB + row0 + r) * 2048 + (size_t)e0 * 2 + q * 8),
            v, __ATOMIC_RELAXED, __HIP_MEMORY_SCOPE_AGENT);
      }
      stageC(t + 1, 2, (fb + 2) % NBUF);
      stageC(t + 1, 3, (fb + 3) % NBUF);
      asm volatile("s_waitcnt vmcnt(6)" ::: "memory");   // FIFO: publish retired
      __builtin_amdgcn_s_barrier();                      // ...for all waves
      if (tid == 0)
        __hip_atomic_store(flags + (size_t)wg * 64, (unsigned)(t + 1),
                           __ATOMIC_RELAXED, __HIP_MEMORY_SCOPE_AGENT);
    }
  }
}

__global__ __launch_bounds__(256) void lstm_loss_part(
    const float* __restrict__ h, const float* __restrict__ tgt, float* __restrict__ partials)
{
  __shared__ float lds[4];
  int tid = threadIdx.x;
  float s = 0.f;
  int base = blockIdx.x * 1024 + tid;
#pragma unroll
  for (int q = 0; q < 4; ++q) {
    int idx = base + (q << 8);
    s += fabsf(h[idx] - tgt[idx]);
  }
#pragma unroll
  for (int off = 32; off > 0; off >>= 1) s += __shfl_down(s, off, 64);
  if ((tid & 63) == 0) lds[tid >> 6] = s;
  __syncthreads();
  if (tid == 0) partials[blockIdx.x] = lds[0] + lds[1] + lds[2] + lds[3];
}

__global__ __launch_bounds__(256) void lstm_loss_fin(
    const float* __restrict__ partials, float* __restrict__ out)
{
  __shared__ float lds[4];
  int tid = threadIdx.x;
  float s = partials[tid];
#pragma unroll
  for (int off = 32; off > 0; off >>= 1) s += __shfl_down(s, off, 64);
  if ((tid & 63) == 0) lds[tid >> 6] = s;
  __syncthreads();
  if (tid == 0) out[0] = (lds[0] + lds[1] + lds[2] + lds[3]) * (1.0f / 262144.0f);
}

extern "C" void kernel_launch(void* const* d_in, const int* in_sizes, int n_in,
                              void* d_out, int out_size, void* d_ws, size_t ws_size,
                              hipStream_t stream) {
  const float* x   = (const float*)d_in[0];
  const float* tgt = (const float*)d_in[1];
  const float* Wih = (const float*)d_in[2];
  const float* Whh = (const float*)d_in[3];

  float* out   = (float*)d_out;
  float* h_out = out + 1;                 // [256*1024]
  float* c_io  = out + 1 + BB * EE;       // [256*1024]

  // ws: xbf (16.8MB) | hroll 32 slots (16.8MB) | partials (1KB) | flags (64KB)
  short* xbf      = (short*)d_ws;
  short* hroll    = (short*)((char*)xbf + (size_t)LL * BB * EE * 2);
  float* partials = (float*)((char*)hroll + (size_t)LL * BB * EE * 2);
  unsigned* flags = (unsigned*)((char*)partials + 1024);

  static bool attr_done = false;
  if (!attr_done) {
    hipFuncSetAttribute((const void*)lstm_rec,
                        hipFuncAttributeMaxDynamicSharedMemorySize, LDS_DYN);
    attr_done = true;
  }

  lstm_prep<<<4096, 256, 0, stream>>>(x, xbf, c_io, flags);

  {
    const short* xbfA = xbf; const float* WihA = Wih; const float* WhhA = Whh;
    short* hrollA = hroll; float* cA = c_io; float* hA = h_out; unsigned* flagsA = flags;
    void* args[] = {&xbfA, &WihA, &WhhA, &hrollA, &cA, &hA, &flagsA};
    hipError_t e = hipLaunchCooperativeKernel((void*)lstm_rec, dim3(256), dim3(512),
                                              args, LDS_DYN, stream);
    if (e != hipSuccess)   // insurance vs silent coop rejection
      lstm_rec<<<256, 512, LDS_DYN, stream>>>(xbf, Wih, Whh, hroll, c_io, h_out, flags);
  }

  lstm_loss_part<<<256, 256, 0, stream>>>(h_out, tgt, partials);
  lstm_loss_fin<<<1, 256, 0, stream>>>(partials, out);
}